// Round 1
// baseline (1177.924 us; speedup 1.0000x reference)
//
#include <hip/hip_runtime.h>

// BlockTT factorized embedding.
// vocab 128000 = 40*50*64 (M), dim 1024 = 8*8*16 (N), rank 8.
// out[t][(n0*8+n1)*16+n2] = sum_{r,s} core0[0][i0][n0][r]*core1[r][i1][n1][s]*core2[s][i2][n2]
//
// One wave per token; lane = p = (n0,n1). All index-derived addresses are
// wave-uniform (readfirstlane) so core2 reads are scalar/broadcast. No LDS.

__global__ __launch_bounds__(256)
void ftt_embed_kernel(const int* __restrict__ indices,
                      const float* __restrict__ core0,
                      const float* __restrict__ core1,
                      const float* __restrict__ core2,
                      float* __restrict__ out,
                      int num_tokens)
{
    const int lane  = threadIdx.x & 63;
    const int token = (int)((blockIdx.x * blockDim.x + threadIdx.x) >> 6);
    if (token >= num_tokens) return;

    int idx = indices[token];
    idx = __builtin_amdgcn_readfirstlane(idx);
    // memory-safety clamp (also guards against a dtype surprise)
    if (idx < 0) idx = 0;
    if (idx > 127999) idx = 127999;

    const int i0  = idx / 3200;          // M1*M2 = 50*64
    const int rem = idx - i0 * 3200;
    const int i1  = rem >> 6;            // /64
    const int i2  = rem & 63;            // %64

    const int n0 = lane >> 3;
    const int n1 = lane & 7;

    // cur[r] = core0[0][i0][n0][r]   (layout [1][40][8][8])
    float cur[8];
    {
        const float4* p = reinterpret_cast<const float4*>(core0 + i0 * 64 + n0 * 8);
        float4 a = p[0], b = p[1];
        cur[0] = a.x; cur[1] = a.y; cur[2] = a.z; cur[3] = a.w;
        cur[4] = b.x; cur[5] = b.y; cur[6] = b.z; cur[7] = b.w;
    }

    // tmp[s] = sum_r cur[r] * core1[r][i1][n1][s]   (layout [8][50][8][8])
    float tmp[8] = {0.f,0.f,0.f,0.f,0.f,0.f,0.f,0.f};
    const float* c1base = core1 + i1 * 64 + n1 * 8;
    #pragma unroll
    for (int r = 0; r < 8; ++r) {
        const float4* p = reinterpret_cast<const float4*>(c1base + r * 3200);
        float4 a = p[0], b = p[1];
        const float cr = cur[r];
        tmp[0] = fmaf(cr, a.x, tmp[0]);
        tmp[1] = fmaf(cr, a.y, tmp[1]);
        tmp[2] = fmaf(cr, a.z, tmp[2]);
        tmp[3] = fmaf(cr, a.w, tmp[3]);
        tmp[4] = fmaf(cr, b.x, tmp[4]);
        tmp[5] = fmaf(cr, b.y, tmp[5]);
        tmp[6] = fmaf(cr, b.z, tmp[6]);
        tmp[7] = fmaf(cr, b.w, tmp[7]);
    }

    // o[n2] = sum_s tmp[s] * core2[s][i2][n2]   (layout [8][64][16][1])
    float o[16];
    #pragma unroll
    for (int j = 0; j < 16; ++j) o[j] = 0.f;
    const float* c2base = core2 + i2 * 16;
    #pragma unroll
    for (int s = 0; s < 8; ++s) {
        const float4* p = reinterpret_cast<const float4*>(c2base + s * 1024);
        float4 a = p[0], b = p[1], c = p[2], d = p[3];
        const float ts = tmp[s];
        o[0]  = fmaf(ts, a.x, o[0]);
        o[1]  = fmaf(ts, a.y, o[1]);
        o[2]  = fmaf(ts, a.z, o[2]);
        o[3]  = fmaf(ts, a.w, o[3]);
        o[4]  = fmaf(ts, b.x, o[4]);
        o[5]  = fmaf(ts, b.y, o[5]);
        o[6]  = fmaf(ts, b.z, o[6]);
        o[7]  = fmaf(ts, b.w, o[7]);
        o[8]  = fmaf(ts, c.x, o[8]);
        o[9]  = fmaf(ts, c.y, o[9]);
        o[10] = fmaf(ts, c.z, o[10]);
        o[11] = fmaf(ts, c.w, o[11]);
        o[12] = fmaf(ts, d.x, o[12]);
        o[13] = fmaf(ts, d.y, o[13]);
        o[14] = fmaf(ts, d.z, o[14]);
        o[15] = fmaf(ts, d.w, o[15]);
    }

    // lane p owns 16 contiguous output floats
    float4* op = reinterpret_cast<float4*>(out + (size_t)token * 1024 + lane * 16);
    op[0] = make_float4(o[0],  o[1],  o[2],  o[3]);
    op[1] = make_float4(o[4],  o[5],  o[6],  o[7]);
    op[2] = make_float4(o[8],  o[9],  o[10], o[11]);
    op[3] = make_float4(o[12], o[13], o[14], o[15]);
}

extern "C" void kernel_launch(void* const* d_in, const int* in_sizes, int n_in,
                              void* d_out, int out_size, void* d_ws, size_t ws_size,
                              hipStream_t stream)
{
    const int*   indices = (const int*)  d_in[0];
    const float* core0   = (const float*)d_in[1];
    const float* core1   = (const float*)d_in[2];
    const float* core2   = (const float*)d_in[3];
    float*       out     = (float*)      d_out;

    const int num_tokens = out_size / 1024;           // 262144
    const long long threads = (long long)num_tokens * 64;
    const int blocks = (int)((threads + 255) / 256);  // 65536
    ftt_embed_kernel<<<blocks, 256, 0, stream>>>(indices, core0, core1, core2, out, num_tokens);
}